// Round 5
// baseline (2246.076 us; speedup 1.0000x reference)
//
#include <hip/hip_runtime.h>
#include <hip/hip_bf16.h>
#include <cstdint>

#define B_ 256
#define D_ 128
#define T_ 512
#define H_ 256
#define C_ 10
#define S32 0xFFFFFFFFu

using f32x4 = __attribute__((ext_vector_type(4))) float;
using s16x8 = __attribute__((ext_vector_type(8))) short;
using u32x4 = __attribute__((ext_vector_type(4))) unsigned int;

__device__ __forceinline__ unsigned short f2bf(float f) {
    union { float f; uint32_t u; } a; a.f = f;
    uint32_t u = a.u;
    uint32_t r = (u + 0x7fffu + ((u >> 16) & 1u)) >> 16;   // RNE
    return (unsigned short)r;
}

__device__ __forceinline__ float sigm(float v) { return 1.0f / (1.0f + __expf(-v)); }

// LDS-only barrier: does NOT drain vmcnt -> in-flight global loads/stores
// keep flying across it.
__device__ __forceinline__ void lds_barrier() {
    asm volatile("s_waitcnt lgkmcnt(0)" ::: "memory");
    __builtin_amdgcn_sched_barrier(0);
    __builtin_amdgcn_s_barrier();
    __builtin_amdgcn_sched_barrier(0);
}

// ---------------------------------------------------------------------------
// Kernel 1: transpose x [B][D][T] f32  ->  xt [T][B][D] bf16
// ---------------------------------------------------------------------------
__global__ void xt_kernel(const float* __restrict__ x, unsigned short* __restrict__ xt) {
    __shared__ unsigned short tile[128][66];
    const int b  = blockIdx.x >> 3;
    const int t0 = (blockIdx.x & 7) << 6;
    const int tid = threadIdx.x;
    const int j  = tid & 63;
    const int dq = tid >> 6;

#pragma unroll
    for (int it = 0; it < 32; ++it) {
        int d = it * 4 + dq;
        tile[d][j] = f2bf(x[(size_t)(b * D_ + d) * T_ + t0 + j]);
    }
    __syncthreads();

    uint32_t* xt32 = (uint32_t*)xt;
#pragma unroll
    for (int it = 0; it < 16; ++it) {
        int tl = it * 4 + dq;
        int dp = j;
        uint32_t lo = tile[2 * dp][tl];
        uint32_t hi = tile[2 * dp + 1][tl];
        xt32[(size_t)((t0 + tl) * B_ + b) * (D_ / 2) + dp] = lo | (hi << 16);
    }
}

// ---------------------------------------------------------------------------
// Kernel 2: persistent LSTM recurrence — clique-of-4 (XCD-pure), all gates
// per lane, zero barriers except one lgkm-only per step.
// 64 blocks: bc = blockIdx&15 (batch chunk), hcq = blockIdx>>4 (unit quarter)
//   -> clique {bc, bc+16, bc+32, bc+48} all == bc (mod 8): one XCD.
// Per-step vmem ledger (per wave, issue order -> vmcnt retires in order):
//   [hv: 6 peer-quarter loads][xa: 4 x loads][st: 4 agent stores]
//   steady wait = vmcnt(4): retires hv+xa, NEVER the store acks.
// Own 64-unit quarter bypasses the MALL entirely via LDS double buffer.
// Peer data self-validates (0xFF sentinel = bf16 NaN); retry path only
// re-issues the 6 peer loads and fully drains.
// ---------------------------------------------------------------------------
#define ISSUE_HV()                                                                     \
    do {                                                                               \
        asm volatile("global_load_dwordx4 %0, %1, off sc1" : "=v"(hv0) : "v"(hp0));    \
        asm volatile("global_load_dwordx4 %0, %1, off sc1" : "=v"(hv1) : "v"(hp1));    \
        asm volatile("global_load_dwordx4 %0, %1, off sc1" : "=v"(hv2) : "v"(hp2));    \
        asm volatile("global_load_dwordx4 %0, %1, off sc1" : "=v"(hv3) : "v"(hp3));    \
        asm volatile("global_load_dwordx4 %0, %1, off sc1" : "=v"(hv4) : "v"(hp4));    \
        asm volatile("global_load_dwordx4 %0, %1, off sc1" : "=v"(hv5) : "v"(hp5));    \
    } while (0)

#define ISSUE_XA(p_)                                                                   \
    do {                                                                               \
        asm volatile("global_load_dwordx4 %0, %1, off"            : "=v"(xa0) : "v"(p_)); \
        asm volatile("global_load_dwordx4 %0, %1, off offset:64"  : "=v"(xa1) : "v"(p_)); \
        asm volatile("global_load_dwordx4 %0, %1, off offset:128" : "=v"(xa2) : "v"(p_)); \
        asm volatile("global_load_dwordx4 %0, %1, off offset:192" : "=v"(xa3) : "v"(p_)); \
    } while (0)

__global__ void __launch_bounds__(256, 1) lstm_kernel(
    const float* __restrict__ Wgx, const float* __restrict__ Wix,
    const float* __restrict__ Wfx, const float* __restrict__ Wox,
    const float* __restrict__ Wgh, const float* __restrict__ Wih,
    const float* __restrict__ Wfh, const float* __restrict__ Woh,
    const float* __restrict__ bg,  const float* __restrict__ bi,
    const float* __restrict__ bf2, const float* __restrict__ bo,
    const unsigned short* __restrict__ xt,
    unsigned short* __restrict__ hbuf,
    float* __restrict__ hfin)
{
    __shared__ unsigned short h_s[2][16][72];

    const int tid  = threadIdx.x;
    const int bc   = blockIdx.x & 15;      // batch chunk  (XCD-pure cliques)
    const int hcq  = blockIdx.x >> 4;      // unit quarter
    const int wave = tid >> 6;
    const int lane = tid & 63;
    const int mrow = lane & 15;
    const int quad = lane >> 4;
    const int u    = hcq * 64 + wave * 16 + mrow;   // this lane's output unit

    // peer K-slice table: global h slices 0..7 minus own {2hcq, 2hcq+1}
    int pi[6];
    {
        int ix = 0;
        for (int s = 0; s < 8; ++s)
            if ((s >> 1) != hcq) pi[ix++] = s;
    }

    const float* WxA[4] = {Wgx, Wix, Wfx, Wox};
    const float* WhA[4] = {Wgh, Wih, Wfh, Woh};

    // ---- one-time weight gather (B-frags, permuted to match hv order) ----
    s16x8 wfx[4][4], wfp[4][6], wfo[4][2];
#pragma unroll
    for (int g = 0; g < 4; ++g) {
#pragma unroll
        for (int ks = 0; ks < 4; ++ks) {
            const float* src = WxA[g] + (size_t)(ks * 32 + quad * 8) * H_ + u;
            s16x8 v;
#pragma unroll
            for (int j = 0; j < 8; ++j) v[j] = (short)f2bf(src[(size_t)j * H_]);
            wfx[g][ks] = v;
        }
#pragma unroll
        for (int i = 0; i < 6; ++i) {
            const float* src = WhA[g] + (size_t)(pi[i] * 32 + quad * 8) * H_ + u;
            s16x8 v;
#pragma unroll
            for (int j = 0; j < 8; ++j) v[j] = (short)f2bf(src[(size_t)j * H_]);
            wfp[g][i] = v;
        }
#pragma unroll
        for (int j2 = 0; j2 < 2; ++j2) {
            const float* src = WhA[g] + (size_t)((hcq * 2 + j2) * 32 + quad * 8) * H_ + u;
            s16x8 v;
#pragma unroll
            for (int j = 0; j < 8; ++j) v[j] = (short)f2bf(src[(size_t)j * H_]);
            wfo[g][j2] = v;
        }
    }

    const float bs0 = bg[u], bs1 = bi[u], bs2 = bf2[u], bs3 = bo[u];

    float cst[4] = {0.f, 0.f, 0.f, 0.f};
    float hst[4] = {0.f, 0.f, 0.f, 0.f};

    u32x4 hv0, hv1, hv2, hv3, hv4, hv5;
    u32x4 xa0, xa1, xa2, xa3;

    const size_t arow = (size_t)(bc * 16 + mrow);
    const size_t HSTRIDE = (size_t)B_ * H_;           // elems per slot

    // peer-load pointers (slot 0); advanced AFTER each step's check
    const unsigned short* hp0 = hbuf + arow * H_ + pi[0] * 32 + quad * 8;
    const unsigned short* hp1 = hbuf + arow * H_ + pi[1] * 32 + quad * 8;
    const unsigned short* hp2 = hbuf + arow * H_ + pi[2] * 32 + quad * 8;
    const unsigned short* hp3 = hbuf + arow * H_ + pi[3] * 32 + quad * 8;
    const unsigned short* hp4 = hbuf + arow * H_ + pi[4] * 32 + quad * 8;
    const unsigned short* hp5 = hbuf + arow * H_ + pi[5] * 32 + quad * 8;
    const unsigned short* xp  = xt + arow * D_ + quad * 8;

    // =====================  prologue: t = 0  =============================
    ISSUE_XA(xp);
    asm volatile("s_waitcnt vmcnt(0)" ::: "memory");
    __builtin_amdgcn_sched_barrier(0);

    f32x4 acc[4];
    acc[0] = (f32x4){bs0, bs0, bs0, bs0};
    acc[1] = (f32x4){bs1, bs1, bs1, bs1};
    acc[2] = (f32x4){bs2, bs2, bs2, bs2};
    acc[3] = (f32x4){bs3, bs3, bs3, bs3};
    {
        s16x8 A0 = __builtin_bit_cast(s16x8, xa0);
        s16x8 A1 = __builtin_bit_cast(s16x8, xa1);
        s16x8 A2 = __builtin_bit_cast(s16x8, xa2);
        s16x8 A3 = __builtin_bit_cast(s16x8, xa3);
#pragma unroll
        for (int g = 0; g < 4; ++g) {
            acc[g] = __builtin_amdgcn_mfma_f32_16x16x32_bf16(A0, wfx[g][0], acc[g], 0, 0, 0);
            acc[g] = __builtin_amdgcn_mfma_f32_16x16x32_bf16(A1, wfx[g][1], acc[g], 0, 0, 0);
            acc[g] = __builtin_amdgcn_mfma_f32_16x16x32_bf16(A2, wfx[g][2], acc[g], 0, 0, 0);
            acc[g] = __builtin_amdgcn_mfma_f32_16x16x32_bf16(A3, wfx[g][3], acc[g], 0, 0, 0);
        }
    }
#pragma unroll
    for (int r = 0; r < 4; ++r) {
        float gg = 2.0f * sigm(2.0f * acc[0][r]) - 1.0f;
        float ii = sigm(acc[1][r]), ff = sigm(acc[2][r]), oo = sigm(acc[3][r]);
        cst[r] = gg * ii + cst[r] * ff;
        hst[r] = (2.0f * sigm(2.0f * cst[r]) - 1.0f) * oo;
    }
#pragma unroll
    for (int r = 0; r < 4; ++r)
        h_s[0][quad * 4 + r][wave * 16 + mrow] = f2bf(hst[r]);

    uint64_t stv[4];
#pragma unroll
    for (int r = 0; r < 4; ++r) {
        uint32_t hb = f2bf(hst[r]);
        uint32_t p2 = hb | ((uint32_t)__shfl_down((int)hb, 1, 64) << 16);
        uint32_t q2 = (uint32_t)__shfl_down((int)p2, 2, 64);
        stv[r] = ((uint64_t)q2 << 32) | (uint64_t)p2;
    }
    ISSUE_HV();                 // slot 0 peers (race-tolerant)
    xp += (size_t)B_ * D_;
    ISSUE_XA(xp);               // xa(1)
    __builtin_amdgcn_sched_barrier(0);
#pragma unroll
    for (int r = 0; r < 4; ++r)
        if ((mrow & 3) == 0)
            __hip_atomic_store((uint64_t*)(hbuf + (size_t)(bc * 16 + quad * 4 + r) * H_ + (u & ~3)),
                               stv[r], __ATOMIC_RELAXED, __HIP_MEMORY_SCOPE_AGENT);
    __builtin_amdgcn_sched_barrier(0);

    // =====================  steady loop t = 1..511  ======================
    for (int t = 1; t < T_; ++t) {
        lds_barrier();                                   // prev ds_writes visible
        const int pr = (t - 1) & 1;
        s16x8 ha0 = *(const s16x8*)&h_s[pr][mrow][quad * 8];
        s16x8 ha1 = *(const s16x8*)&h_s[pr][mrow][32 + quad * 8];

        // hv (oldest 6) + xa (next 4) ready; store acks (newest 4) NOT waited
        asm volatile("s_waitcnt vmcnt(4)" ::: "memory");
        __builtin_amdgcn_sched_barrier(0);

        // sentinel check on peer data; slow path fully drains + re-issues
        for (;;) {
            uint32_t m = 0;
#pragma unroll
            for (int i = 0; i < 4; ++i) {
                m = m > hv0[i] ? m : hv0[i];  m = m > hv1[i] ? m : hv1[i];
                m = m > hv2[i] ? m : hv2[i];  m = m > hv3[i] ? m : hv3[i];
                m = m > hv4[i] ? m : hv4[i];  m = m > hv5[i] ? m : hv5[i];
            }
            if (__all(m != S32)) break;
            __builtin_amdgcn_s_sleep(1);
            ISSUE_HV();
            asm volatile("s_waitcnt vmcnt(0)" ::: "memory");
            __builtin_amdgcn_sched_barrier(0);
        }
        // advance peer pointers to slot t (issued at this step's end)
        hp0 += HSTRIDE; hp1 += HSTRIDE; hp2 += HSTRIDE;
        hp3 += HSTRIDE; hp4 += HSTRIDE; hp5 += HSTRIDE;

        acc[0] = (f32x4){bs0, bs0, bs0, bs0};
        acc[1] = (f32x4){bs1, bs1, bs1, bs1};
        acc[2] = (f32x4){bs2, bs2, bs2, bs2};
        acc[3] = (f32x4){bs3, bs3, bs3, bs3};

        // peer h-MFMAs (static register indexing; weights pre-permuted)
#pragma unroll
        for (int g = 0; g < 4; ++g) {
            acc[g] = __builtin_amdgcn_mfma_f32_16x16x32_bf16(__builtin_bit_cast(s16x8, hv0), wfp[g][0], acc[g], 0, 0, 0);
            acc[g] = __builtin_amdgcn_mfma_f32_16x16x32_bf16(__builtin_bit_cast(s16x8, hv1), wfp[g][1], acc[g], 0, 0, 0);
            acc[g] = __builtin_amdgcn_mfma_f32_16x16x32_bf16(__builtin_bit_cast(s16x8, hv2), wfp[g][2], acc[g], 0, 0, 0);
            acc[g] = __builtin_amdgcn_mfma_f32_16x16x32_bf16(__builtin_bit_cast(s16x8, hv3), wfp[g][3], acc[g], 0, 0, 0);
            acc[g] = __builtin_amdgcn_mfma_f32_16x16x32_bf16(__builtin_bit_cast(s16x8, hv4), wfp[g][4], acc[g], 0, 0, 0);
            acc[g] = __builtin_amdgcn_mfma_f32_16x16x32_bf16(__builtin_bit_cast(s16x8, hv5), wfp[g][5], acc[g], 0, 0, 0);
        }
        // own-quarter h-MFMAs from LDS
#pragma unroll
        for (int g = 0; g < 4; ++g) {
            acc[g] = __builtin_amdgcn_mfma_f32_16x16x32_bf16(ha0, wfo[g][0], acc[g], 0, 0, 0);
            acc[g] = __builtin_amdgcn_mfma_f32_16x16x32_bf16(ha1, wfo[g][1], acc[g], 0, 0, 0);
        }
        // x-MFMAs
        {
            s16x8 A0 = __builtin_bit_cast(s16x8, xa0);
            s16x8 A1 = __builtin_bit_cast(s16x8, xa1);
            s16x8 A2 = __builtin_bit_cast(s16x8, xa2);
            s16x8 A3 = __builtin_bit_cast(s16x8, xa3);
#pragma unroll
            for (int g = 0; g < 4; ++g) {
                acc[g] = __builtin_amdgcn_mfma_f32_16x16x32_bf16(A0, wfx[g][0], acc[g], 0, 0, 0);
                acc[g] = __builtin_amdgcn_mfma_f32_16x16x32_bf16(A1, wfx[g][1], acc[g], 0, 0, 0);
                acc[g] = __builtin_amdgcn_mfma_f32_16x16x32_bf16(A2, wfx[g][2], acc[g], 0, 0, 0);
                acc[g] = __builtin_amdgcn_mfma_f32_16x16x32_bf16(A3, wfx[g][3], acc[g], 0, 0, 0);
            }
        }

        // activation fully in-register (rows quad*4+r, unit mrow)
#pragma unroll
        for (int r = 0; r < 4; ++r) {
            float gg = 2.0f * sigm(2.0f * acc[0][r]) - 1.0f;
            float ii = sigm(acc[1][r]), ff = sigm(acc[2][r]), oo = sigm(acc[3][r]);
            cst[r] = gg * ii + cst[r] * ff;
            hst[r] = (2.0f * sigm(2.0f * cst[r]) - 1.0f) * oo;
        }

        // own quarter -> LDS (other buffer), peers -> packed u64
        const int cw = t & 1;
#pragma unroll
        for (int r = 0; r < 4; ++r)
            h_s[cw][quad * 4 + r][wave * 16 + mrow] = f2bf(hst[r]);
#pragma unroll
        for (int r = 0; r < 4; ++r) {
            uint32_t hb = f2bf(hst[r]);
            uint32_t p2 = hb | ((uint32_t)__shfl_down((int)hb, 1, 64) << 16);
            uint32_t q2 = (uint32_t)__shfl_down((int)p2, 2, 64);
            stv[r] = ((uint64_t)q2 << 32) | (uint64_t)p2;
        }

        // end-block vmem: [hv(slot t)] [xa(t+1)] [stores(slot t)] - stores newest
        ISSUE_HV();
        if (t + 1 < T_) xp += (size_t)B_ * D_;
        ISSUE_XA(xp);
        __builtin_amdgcn_sched_barrier(0);
        {
            unsigned short* sbase = hbuf + (size_t)t * HSTRIDE;
#pragma unroll
            for (int r = 0; r < 4; ++r)
                if ((mrow & 3) == 0)
                    __hip_atomic_store((uint64_t*)(sbase + (size_t)(bc * 16 + quad * 4 + r) * H_ + (u & ~3)),
                                       stv[r], __ATOMIC_RELAXED, __HIP_MEMORY_SCOPE_AGENT);
        }
        __builtin_amdgcn_sched_barrier(0);
    }

#pragma unroll
    for (int r = 0; r < 4; ++r)
        hfin[(size_t)(bc * 16 + quad * 4 + r) * H_ + u] = hst[r];
}

// ---------------------------------------------------------------------------
// Kernel 3: out = h_final @ W_ph + b_p
// ---------------------------------------------------------------------------
__global__ void proj_kernel(const float* __restrict__ hfin, const float* __restrict__ Wph,
                            const float* __restrict__ bp, float* __restrict__ out) {
    int gid = blockIdx.x * 256 + threadIdx.x;
    if (gid >= B_ * C_) return;
    int b = gid / C_, cc = gid % C_;
    float acc = bp[cc];
#pragma unroll 8
    for (int u = 0; u < H_; ++u)
        acc += hfin[(size_t)b * H_ + u] * Wph[(size_t)u * C_ + cc];
    out[gid] = acc;
}

// ---------------------------------------------------------------------------
extern "C" void kernel_launch(void* const* d_in, const int* in_sizes, int n_in,
                              void* d_out, int out_size, void* d_ws, size_t ws_size,
                              hipStream_t stream) {
    const float* x   = (const float*)d_in[0];
    const float* Wgx = (const float*)d_in[1];
    const float* Wix = (const float*)d_in[2];
    const float* Wfx = (const float*)d_in[3];
    const float* Wox = (const float*)d_in[4];
    const float* Wgh = (const float*)d_in[5];
    const float* Wih = (const float*)d_in[6];
    const float* Wfh = (const float*)d_in[7];
    const float* Woh = (const float*)d_in[8];
    const float* bg  = (const float*)d_in[9];
    const float* bi  = (const float*)d_in[10];
    const float* bf2 = (const float*)d_in[11];
    const float* bo  = (const float*)d_in[12];
    const float* Wph = (const float*)d_in[13];
    const float* bp  = (const float*)d_in[14];

    const size_t hbuf_bytes = (size_t)T_ * B_ * H_ * 2;   // 64 MB bf16 [T][B][H]

    char* ws = (char*)d_ws;
    unsigned short* hbuf = (unsigned short*)ws;
    float*          hfin = (float*)(ws + hbuf_bytes);
    unsigned short* xt   = (unsigned short*)(ws + hbuf_bytes + (size_t)B_ * H_ * sizeof(float));

    // sentinel-fill the h exchange buffer (bf16 NaN pattern 0xFFFF)
    hipMemsetAsync(hbuf, 0xFF, hbuf_bytes, stream);

    xt_kernel<<<B_ * (T_ / 64), 256, 0, stream>>>(x, xt);

    lstm_kernel<<<64, 256, 0, stream>>>(Wgx, Wix, Wfx, Wox, Wgh, Wih, Wfh, Woh,
                                        bg, bi, bf2, bo, xt, hbuf, hfin);

    proj_kernel<<<(B_ * C_ + 255) / 256, 256, 0, stream>>>(hfin, Wph, bp, (float*)d_out);
}

// Round 6
// 1745.139 us; speedup vs baseline: 1.2870x; 1.2870x over previous
//
#include <hip/hip_runtime.h>
#include <hip/hip_bf16.h>
#include <cstdint>

#define B_ 256
#define D_ 128
#define T_ 512
#define H_ 256
#define C_ 10
#define S32 0xFFFFFFFFu

using f32x4 = __attribute__((ext_vector_type(4))) float;
using s16x8 = __attribute__((ext_vector_type(8))) short;
using u32x4 = __attribute__((ext_vector_type(4))) unsigned int;

__device__ __forceinline__ unsigned short f2bf(float f) {
    union { float f; uint32_t u; } a; a.f = f;
    uint32_t u = a.u;
    uint32_t r = (u + 0x7fffu + ((u >> 16) & 1u)) >> 16;   // RNE
    return (unsigned short)r;
}

__device__ __forceinline__ float sigm(float v) { return 1.0f / (1.0f + __expf(-v)); }

// ---------------------------------------------------------------------------
// Kernel 1: transpose x [B][D][T] f32  ->  xt [T][B][D] bf16
// ---------------------------------------------------------------------------
__global__ void xt_kernel(const float* __restrict__ x, unsigned short* __restrict__ xt) {
    __shared__ unsigned short tile[128][66];
    const int b  = blockIdx.x >> 3;
    const int t0 = (blockIdx.x & 7) << 6;
    const int tid = threadIdx.x;
    const int j  = tid & 63;
    const int dq = tid >> 6;

#pragma unroll
    for (int it = 0; it < 32; ++it) {
        int d = it * 4 + dq;
        tile[d][j] = f2bf(x[(size_t)(b * D_ + d) * T_ + t0 + j]);
    }
    __syncthreads();

    uint32_t* xt32 = (uint32_t*)xt;
#pragma unroll
    for (int it = 0; it < 16; ++it) {
        int tl = it * 4 + dq;
        int dp = j;
        uint32_t lo = tile[2 * dp][tl];
        uint32_t hi = tile[2 * dp + 1][tl];
        xt32[(size_t)((t0 + tl) * B_ + b) * (D_ / 2) + dp] = lo | (hi << 16);
    }
}

// ---------------------------------------------------------------------------
// Kernel 2: persistent LSTM recurrence.
// HYBRID of the two measured-fast pieces:
//   * grid/exchange: 256 blocks = 16 batch-chunks (bc) x 16 unit-slices (hc),
//     16-producer cliques (the R0/R1 family measured at ~5100 cy/step,
//     2x faster than every 64-block variant).
//   * block body: ONE wave owning 16 rows x 16 units x ALL 4 gates
//     (48 mfma_16x16x32_bf16, weights in 192 VGPRs). All 4 gates land in
//     the same lane -> activation fully in-register. Zero LDS, zero
//     barriers, single s_waitcnt vmcnt(0) per step.
// h exchange: per-step slot in hbuf (bf16 [T][B][H], 0xFF = bf16-NaN
// sentinel, unreachable for tanh*sigmoid outputs). Producers: 4 predicated
// packed-u64 relaxed agent stores. Consumers: h loaded DIRECTLY into MFMA
// A-fragments with sc1 dwordx4 loads (L2-bypass: retries must not hit a
// stale cached sentinel), early-issued at the end of the previous step,
// re-issued on sentinel. Stores are issued BEFORE the next hv issue so
// own-block words are in-order at the MALL.
// Per-step vmem ledger (issue order): [st 4][hv 8][xa 4]; one vmcnt(0) at
// the top of the step retires all (everything is ~a full step old).
// ---------------------------------------------------------------------------
#define ISSUE_HV(base_)                                                                            \
    do {                                                                                           \
        const unsigned short* hsrc_ = (base_);                                                     \
        asm volatile("global_load_dwordx4 %0, %1, off sc1"            : "=v"(hv[0]) : "v"(hsrc_)); \
        asm volatile("global_load_dwordx4 %0, %1, off offset:64 sc1"  : "=v"(hv[1]) : "v"(hsrc_)); \
        asm volatile("global_load_dwordx4 %0, %1, off offset:128 sc1" : "=v"(hv[2]) : "v"(hsrc_)); \
        asm volatile("global_load_dwordx4 %0, %1, off offset:192 sc1" : "=v"(hv[3]) : "v"(hsrc_)); \
        asm volatile("global_load_dwordx4 %0, %1, off offset:256 sc1" : "=v"(hv[4]) : "v"(hsrc_)); \
        asm volatile("global_load_dwordx4 %0, %1, off offset:320 sc1" : "=v"(hv[5]) : "v"(hsrc_)); \
        asm volatile("global_load_dwordx4 %0, %1, off offset:384 sc1" : "=v"(hv[6]) : "v"(hsrc_)); \
        asm volatile("global_load_dwordx4 %0, %1, off offset:448 sc1" : "=v"(hv[7]) : "v"(hsrc_)); \
    } while (0)

#define ISSUE_XA(p_)                                                                              \
    do {                                                                                          \
        const unsigned short* xsrc_ = (p_);                                                       \
        asm volatile("global_load_dwordx4 %0, %1, off"            : "=v"(xa[0]) : "v"(xsrc_));    \
        asm volatile("global_load_dwordx4 %0, %1, off offset:64"  : "=v"(xa[1]) : "v"(xsrc_));    \
        asm volatile("global_load_dwordx4 %0, %1, off offset:128" : "=v"(xa[2]) : "v"(xsrc_));    \
        asm volatile("global_load_dwordx4 %0, %1, off offset:192" : "=v"(xa[3]) : "v"(xsrc_));    \
    } while (0)

__global__ void __launch_bounds__(64, 1) lstm_kernel(
    const float* __restrict__ Wgx, const float* __restrict__ Wix,
    const float* __restrict__ Wfx, const float* __restrict__ Wox,
    const float* __restrict__ Wgh, const float* __restrict__ Wih,
    const float* __restrict__ Wfh, const float* __restrict__ Woh,
    const float* __restrict__ bg,  const float* __restrict__ bi,
    const float* __restrict__ bf2, const float* __restrict__ bo,
    const unsigned short* __restrict__ xt,
    unsigned short* __restrict__ hbuf,
    float* __restrict__ hfin)
{
    const int lane = threadIdx.x & 63;
    const int bc   = blockIdx.x & 15;      // batch chunk (16 rows) — R0 clique shape
    const int hc   = blockIdx.x >> 4;      // unit slice (16 units)
    const int mrow = lane & 15;
    const int quad = lane >> 4;
    const int u    = hc * 16 + mrow;       // this lane's output unit

    const float* WxA[4] = {Wgx, Wix, Wfx, Wox};
    const float* WhA[4] = {Wgh, Wih, Wfh, Woh};

    // ---- one-time: all 48 B-fragments into registers --------------------
    // B-frag (proven in R3/R5): lane holds B[k = ks*32 + quad*8 + j][col = u]
    s16x8 wf[4][12];
#pragma unroll
    for (int g = 0; g < 4; ++g) {
#pragma unroll
        for (int ks = 0; ks < 12; ++ks) {
            const float* src = (ks < 4)
                ? (WxA[g] + (size_t)(ks * 32 + quad * 8) * H_ + u)
                : (WhA[g] + (size_t)((ks - 4) * 32 + quad * 8) * H_ + u);
            s16x8 v;
#pragma unroll
            for (int j = 0; j < 8; ++j)
                v[j] = (short)f2bf(src[(size_t)j * H_]);
            wf[g][ks] = v;
        }
    }

    const float bs0 = bg[u], bs1 = bi[u], bs2 = bf2[u], bs3 = bo[u];

    float cst[4] = {0.f, 0.f, 0.f, 0.f};
    float hst[4] = {0.f, 0.f, 0.f, 0.f};

    u32x4 hv[8];
    u32x4 xa[4];

    const size_t arow    = (size_t)(bc * 16 + mrow);   // A-fragment source row
    const size_t HSTRIDE = (size_t)B_ * H_;            // elems per h slot

    // =====================  prologue: t = 0  =============================
    ISSUE_XA(xt + arow * D_ + quad * 8);
    asm volatile("s_waitcnt vmcnt(0)" ::: "memory");
    __builtin_amdgcn_sched_barrier(0);

    f32x4 acc[4];
    acc[0] = (f32x4){bs0, bs0, bs0, bs0};
    acc[1] = (f32x4){bs1, bs1, bs1, bs1};
    acc[2] = (f32x4){bs2, bs2, bs2, bs2};
    acc[3] = (f32x4){bs3, bs3, bs3, bs3};
#pragma unroll
    for (int ks = 0; ks < 4; ++ks) {
        s16x8 A = __builtin_bit_cast(s16x8, xa[ks]);
#pragma unroll
        for (int g = 0; g < 4; ++g)
            acc[g] = __builtin_amdgcn_mfma_f32_16x16x32_bf16(A, wf[g][ks], acc[g], 0, 0, 0);
    }
#pragma unroll
    for (int r = 0; r < 4; ++r) {
        float gg = 2.0f * sigm(2.0f * acc[0][r]) - 1.0f;   // tanh
        float ii = sigm(acc[1][r]), ff = sigm(acc[2][r]), oo = sigm(acc[3][r]);
        cst[r] = gg * ii + cst[r] * ff;
        hst[r] = (2.0f * sigm(2.0f * cst[r]) - 1.0f) * oo;
    }
    // pack + store slot 0, THEN issue hv(slot 0) + xa(1)
#pragma unroll
    for (int r = 0; r < 4; ++r) {
        uint32_t hb = f2bf(hst[r]);
        uint32_t p2 = hb | ((uint32_t)__shfl_down((int)hb, 1, 64) << 16);
        uint32_t q2 = (uint32_t)__shfl_down((int)p2, 2, 64);
        if ((mrow & 3) == 0) {
            uint64_t val = ((uint64_t)q2 << 32) | (uint64_t)p2;
            __hip_atomic_store(
                (uint64_t*)(hbuf + (size_t)(bc * 16 + quad * 4 + r) * H_ + hc * 16 + (mrow & ~3)),
                val, __ATOMIC_RELAXED, __HIP_MEMORY_SCOPE_AGENT);
        }
    }
    __builtin_amdgcn_sched_barrier(0);
    ISSUE_HV(hbuf + arow * H_ + quad * 8);                       // slot 0
    ISSUE_XA(xt + ((size_t)1 * B_ + arow) * D_ + quad * 8);      // xa(1)
    __builtin_amdgcn_sched_barrier(0);

    // =====================  steady loop t = 1..511  ======================
    for (int t = 1; t < T_; ++t) {
        // everything in flight is ~a full step old: st(t-1), hv(t-1), xa(t)
        asm volatile("s_waitcnt vmcnt(0)" ::: "memory");
        __builtin_amdgcn_sched_barrier(0);

        // x-part MFMAs first (independent of hv) — shortens post-detect tail
        acc[0] = (f32x4){bs0, bs0, bs0, bs0};
        acc[1] = (f32x4){bs1, bs1, bs1, bs1};
        acc[2] = (f32x4){bs2, bs2, bs2, bs2};
        acc[3] = (f32x4){bs3, bs3, bs3, bs3};
#pragma unroll
        for (int ks = 0; ks < 4; ++ks) {
            s16x8 A = __builtin_bit_cast(s16x8, xa[ks]);
#pragma unroll
            for (int g = 0; g < 4; ++g)
                acc[g] = __builtin_amdgcn_mfma_f32_16x16x32_bf16(A, wf[g][ks], acc[g], 0, 0, 0);
        }
        __builtin_amdgcn_sched_barrier(0);

        // sentinel poll on the h payload (cheap single-wave check; retry
        // reloads all 8 frags with sc1 and fully drains)
        const unsigned short* hsrc = hbuf + ((size_t)(t - 1) * B_ + arow) * H_ + quad * 8;
        for (;;) {
            uint32_t m = 0;
#pragma unroll
            for (int i = 0; i < 8; ++i) {
                m = m > hv[i].x ? m : hv[i].x;
                m = m > hv[i].y ? m : hv[i].y;
                m = m > hv[i].z ? m : hv[i].z;
                m = m > hv[i].w ? m : hv[i].w;
            }
            if (__all(m != S32)) break;
            __builtin_amdgcn_s_sleep(1);
            ISSUE_HV(hsrc);
            asm volatile("s_waitcnt vmcnt(0)" ::: "memory");
            __builtin_amdgcn_sched_barrier(0);
        }

        // h-part MFMAs straight from the loaded fragments
#pragma unroll
        for (int ks = 0; ks < 8; ++ks) {
            s16x8 A = __builtin_bit_cast(s16x8, hv[ks]);
#pragma unroll
            for (int g = 0; g < 4; ++g)
                acc[g] = __builtin_amdgcn_mfma_f32_16x16x32_bf16(A, wf[g][4 + ks], acc[g], 0, 0, 0);
        }

        // activation fully in-register (rows quad*4+r, unit mrow)
#pragma unroll
        for (int r = 0; r < 4; ++r) {
            float gg = 2.0f * sigm(2.0f * acc[0][r]) - 1.0f;
            float ii = sigm(acc[1][r]), ff = sigm(acc[2][r]), oo = sigm(acc[3][r]);
            cst[r] = gg * ii + cst[r] * ff;
            hst[r] = (2.0f * sigm(2.0f * cst[r]) - 1.0f) * oo;
        }

        // publish h(t): pack unit quads, 4 predicated u64 agent stores,
        // issued BEFORE next hv so own words are in-order at the MALL
        __builtin_amdgcn_sched_barrier(0);
        {
            unsigned short* sbase = hbuf + (size_t)t * HSTRIDE;
#pragma unroll
            for (int r = 0; r < 4; ++r) {
                uint32_t hb = f2bf(hst[r]);
                uint32_t p2 = hb | ((uint32_t)__shfl_down((int)hb, 1, 64) << 16);
                uint32_t q2 = (uint32_t)__shfl_down((int)p2, 2, 64);
                if ((mrow & 3) == 0) {
                    uint64_t val = ((uint64_t)q2 << 32) | (uint64_t)p2;
                    __hip_atomic_store(
                        (uint64_t*)(sbase + (size_t)(bc * 16 + quad * 4 + r) * H_ + hc * 16 + (mrow & ~3)),
                        val, __ATOMIC_RELAXED, __HIP_MEMORY_SCOPE_AGENT);
                }
            }
        }
        __builtin_amdgcn_sched_barrier(0);

        // early-issue next step's h A-fragments (slot t) + xa(t+1, clamped)
        ISSUE_HV(hbuf + (size_t)t * HSTRIDE + arow * H_ + quad * 8);
        {
            int tn = (t + 1 < T_) ? (t + 1) : (T_ - 1);
            ISSUE_XA(xt + ((size_t)tn * B_ + arow) * D_ + quad * 8);
        }
        __builtin_amdgcn_sched_barrier(0);
    }

#pragma unroll
    for (int r = 0; r < 4; ++r)
        hfin[(size_t)(bc * 16 + quad * 4 + r) * H_ + u] = hst[r];
}

// ---------------------------------------------------------------------------
// Kernel 3: out = h_final @ W_ph + b_p
// ---------------------------------------------------------------------------
__global__ void proj_kernel(const float* __restrict__ hfin, const float* __restrict__ Wph,
                            const float* __restrict__ bp, float* __restrict__ out) {
    int gid = blockIdx.x * 256 + threadIdx.x;
    if (gid >= B_ * C_) return;
    int b = gid / C_, cc = gid % C_;
    float acc = bp[cc];
#pragma unroll 8
    for (int u = 0; u < H_; ++u)
        acc += hfin[(size_t)b * H_ + u] * Wph[(size_t)u * C_ + cc];
    out[gid] = acc;
}

// ---------------------------------------------------------------------------
extern "C" void kernel_launch(void* const* d_in, const int* in_sizes, int n_in,
                              void* d_out, int out_size, void* d_ws, size_t ws_size,
                              hipStream_t stream) {
    const float* x   = (const float*)d_in[0];
    const float* Wgx = (const float*)d_in[1];
    const float* Wix = (const float*)d_in[2];
    const float* Wfx = (const float*)d_in[3];
    const float* Wox = (const float*)d_in[4];
    const float* Wgh = (const float*)d_in[5];
    const float* Wih = (const float*)d_in[6];
    const float* Wfh = (const float*)d_in[7];
    const float* Woh = (const float*)d_in[8];
    const float* bg  = (const float*)d_in[9];
    const float* bi  = (const float*)d_in[10];
    const float* bf2 = (const float*)d_in[11];
    const float* bo  = (const float*)d_in[12];
    const float* Wph = (const float*)d_in[13];
    const float* bp  = (const float*)d_in[14];

    const size_t hbuf_bytes = (size_t)T_ * B_ * H_ * 2;   // 64 MB bf16 [T][B][H]

    char* ws = (char*)d_ws;
    unsigned short* hbuf = (unsigned short*)ws;
    float*          hfin = (float*)(ws + hbuf_bytes);
    unsigned short* xt   = (unsigned short*)(ws + hbuf_bytes + (size_t)B_ * H_ * sizeof(float));

    // sentinel-fill the h exchange buffer (bf16 NaN pattern 0xFFFF)
    hipMemsetAsync(hbuf, 0xFF, hbuf_bytes, stream);

    xt_kernel<<<B_ * (T_ / 64), 256, 0, stream>>>(x, xt);

    lstm_kernel<<<256, 64, 0, stream>>>(Wgx, Wix, Wfx, Wox, Wgh, Wih, Wfh, Woh,
                                        bg, bi, bf2, bo, xt, hbuf, hfin);

    proj_kernel<<<(B_ * C_ + 255) / 256, 256, 0, stream>>>(hfin, Wph, bp, (float*)d_out);
}